// Round 1
// baseline (882.432 us; speedup 1.0000x reference)
//
#include <hip/hip_runtime.h>
#include <hip/hip_bf16.h>
#include <stdint.h>

#define QTOT 10000
#define MPAD 10240
#define CDIM 256
#define ODIM 16384

using f32x4  = __attribute__((ext_vector_type(4))) float;
using bf16x8 = __attribute__((ext_vector_type(8))) short;

// ---------------- prep kernels ----------------
__global__ void cvt_f32_bf16(const float* __restrict__ s, __hip_bfloat16* __restrict__ d, int n) {
  for (int i = blockIdx.x * blockDim.x + threadIdx.x; i < n; i += gridDim.x * blockDim.x)
    d[i] = __float2bfloat16(s[i]);
}

// bev [b][c][q] f32 -> bevT [b][q][c] bf16, rows q>=QTOT zero-filled up to MPAD
__global__ __launch_bounds__(256) void transpose_bev(const float* __restrict__ bev,
                                                     __hip_bfloat16* __restrict__ bevT) {
  __shared__ float tl[32][33];
  int tx = threadIdx.x, ty = threadIdx.y;
  int q0 = blockIdx.x * 32, c0 = blockIdx.y * 32, b = blockIdx.z;
#pragma unroll
  for (int i = 0; i < 4; ++i) {
    int c = c0 + ty + i * 8, q = q0 + tx;
    tl[ty + i * 8][tx] = (q < QTOT) ? bev[((size_t)b * CDIM + c) * QTOT + q] : 0.0f;
  }
  __syncthreads();
#pragma unroll
  for (int i = 0; i < 4; ++i) {
    int q = q0 + ty + i * 8, c = c0 + tx;
    bevT[((size_t)b * MPAD + q) * CDIM + c] = __float2bfloat16(tl[tx][ty + i * 8]);
  }
}

// ---------------- GEMM1: param[q][o] = bevT[q][:] . conv_w[o][:] + conv_b[o] ----------------
// A: bevT chunk base [CH][256] bf16 row-major; Bw: conv_w bf16 [16384][256] (B^T pattern)
__global__ __launch_bounds__(256) void gemm_param(const __hip_bfloat16* __restrict__ A,
                                                  const __hip_bfloat16* __restrict__ Bw,
                                                  const float* __restrict__ convb,
                                                  __hip_bfloat16* __restrict__ P) {
  __shared__ __align__(16) unsigned char lsA[128 * 64 * 2];
  __shared__ __align__(16) unsigned char lsB[128 * 64 * 2];
  int t = threadIdx.x, lane = t & 63, w = t >> 6;
  int bm = blockIdx.x, bn = blockIdx.y;
  int wm = (w >> 1) * 64, wn = (w & 1) * 64;
  f32x4 acc[4][4] = {};
  for (int kt = 0; kt < 256; kt += 64) {
#pragma unroll
    for (int i = 0; i < 4; ++i) {
      int lin = i * 256 + t, row = lin >> 3, ks = lin & 7;
      uint4 va = *(const uint4*)(A + (size_t)(bm * 128 + row) * CDIM + kt + ks * 8);
      *(uint4*)(lsA + ((row * 128 + ks * 16) ^ ((row & 7) << 4))) = va;
      uint4 vb = *(const uint4*)(Bw + (size_t)(bn * 128 + row) * CDIM + kt + ks * 8);
      *(uint4*)(lsB + ((row * 128 + ks * 16) ^ ((row & 7) << 4))) = vb;
    }
    __syncthreads();
#pragma unroll
    for (int kk = 0; kk < 2; ++kk) {
      int kb = kk * 64 + ((lane >> 4) << 4);  // byte offset of lane's 8 k-elems
      bf16x8 af[4], bfr[4];
#pragma unroll
      for (int mi = 0; mi < 4; ++mi) {
        int row = wm + mi * 16 + (lane & 15);
        af[mi] = *(const bf16x8*)(lsA + ((row * 128 + kb) ^ ((row & 7) << 4)));
      }
#pragma unroll
      for (int ni = 0; ni < 4; ++ni) {
        int row = wn + ni * 16 + (lane & 15);
        bfr[ni] = *(const bf16x8*)(lsB + ((row * 128 + kb) ^ ((row & 7) << 4)));
      }
#pragma unroll
      for (int mi = 0; mi < 4; ++mi)
#pragma unroll
        for (int ni = 0; ni < 4; ++ni)
          acc[mi][ni] = __builtin_amdgcn_mfma_f32_16x16x32_bf16(af[mi], bfr[ni], acc[mi][ni], 0, 0, 0);
    }
    __syncthreads();
  }
#pragma unroll
  for (int ni = 0; ni < 4; ++ni) {
    int col = bn * 128 + wn + ni * 16 + (lane & 15);
    float cb = convb[col];
#pragma unroll
    for (int mi = 0; mi < 4; ++mi) {
      int rb = bm * 128 + wm + mi * 16 + ((lane >> 4) << 2);
#pragma unroll
      for (int r = 0; r < 4; ++r)
        P[(size_t)(rb + r) * ODIM + col] = __float2bfloat16(acc[mi][ni][r] + cb);
    }
  }
}

// ---------------- phase 2a: mixing + LayerNorm + ReLU ----------------
// per workgroup: 8 pixels. thread t: p = t>>5, c2 pair = 2*(t&31)+{0,1}
__global__ __launch_bounds__(256) void mix_ln(const __hip_bfloat16* __restrict__ P,
                                              const float* __restrict__ pts,
                                              const float* __restrict__ lng,
                                              const float* __restrict__ lnb,
                                              __hip_bfloat16* __restrict__ act,
                                              int b, int q0, int nvalid, int CH) {
  __shared__ __align__(16) float ptsl[2048];
  __shared__ __align__(16) unsigned int paraml[2048];
  int t = threadIdx.x;
  int p_ = t >> 5, cp = t & 31;
  float g0 = lng[2 * cp], g1 = lng[2 * cp + 1];
  float bb0 = lnb[2 * cp], bb1 = lnb[2 * cp + 1];
  for (int px = 0; px < 8; ++px) {
    int row = blockIdx.x * 8 + px;
    if (row >= nvalid) break;
    int q = q0 + row;
    const float4* ps = (const float4*)(pts + ((size_t)b * QTOT + q) * 2048);
#pragma unroll
    for (int i = 0; i < 2; ++i) ((float4*)ptsl)[i * 256 + t] = ps[i * 256 + t];
    for (int g = 0; g < 4; ++g) {
      const uint4* pg = (const uint4*)(P + (size_t)row * ODIM + g * 4096);
      ((uint4*)paraml)[t]       = pg[t];
      ((uint4*)paraml)[256 + t] = pg[256 + t];
      __syncthreads();
      float s0 = 0.f, s1 = 0.f;
      const float* pr = ptsl + p_ * 256 + g * 64;
#pragma unroll 8
      for (int c1 = 0; c1 < 64; ++c1) {
        unsigned int dv = paraml[c1 * 32 + cp];
        float x = pr[c1];
        s0 = fmaf(x, __uint_as_float(dv << 16), s0);
        s1 = fmaf(x, __uint_as_float(dv & 0xffff0000u), s1);
      }
      float s = s0 + s1, ss = fmaf(s0, s0, s1 * s1);
#pragma unroll
      for (int m = 1; m <= 16; m <<= 1) { s += __shfl_xor(s, m); ss += __shfl_xor(ss, m); }
      float mu  = s * 0.015625f;
      float var = ss * 0.015625f - mu * mu;
      float rs  = rsqrtf(var + 1e-5f);
      float a0 = fmaxf(0.f, (s0 - mu) * rs * g0 + bb0);
      float a1 = fmaxf(0.f, (s1 - mu) * rs * g1 + bb1);
      __hip_bfloat162 h;
      h.x = __float2bfloat16(a0);
      h.y = __float2bfloat16(a1);
      *(__hip_bfloat162*)(act + ((size_t)g * CH + row) * 512 + p_ * 64 + 2 * cp) = h;
      __syncthreads();
    }
  }
}

// ---------------- phase 2b: proj GEMM -> outT[b][q][g*64+o] ----------------
__global__ __launch_bounds__(256) void gemm_proj(const __hip_bfloat16* __restrict__ act,
                                                 const __hip_bfloat16* __restrict__ Bp,
                                                 const float* __restrict__ projb,
                                                 float* __restrict__ outT,
                                                 int b, int q0, int CH) {
  __shared__ __align__(16) unsigned char lsA[128 * 64 * 2];
  __shared__ __align__(16) unsigned char lsB[64 * 64 * 2];
  int t = threadIdx.x, lane = t & 63, w = t >> 6;
  int bm = blockIdx.x, g = blockIdx.y;
  int wm = (w >> 1) * 64, wn = (w & 1) * 32;
  const __hip_bfloat16* A = act + (size_t)g * CH * 512;
  f32x4 acc[4][2] = {};
  for (int kt = 0; kt < 512; kt += 64) {
#pragma unroll
    for (int i = 0; i < 4; ++i) {
      int lin = i * 256 + t, row = lin >> 3, ks = lin & 7;
      uint4 va = *(const uint4*)(A + (size_t)(bm * 128 + row) * 512 + kt + ks * 8);
      *(uint4*)(lsA + ((row * 128 + ks * 16) ^ ((row & 7) << 4))) = va;
    }
#pragma unroll
    for (int i = 0; i < 2; ++i) {
      int lin = i * 256 + t, row = lin >> 3, ks = lin & 7;  // row 0..63
      uint4 vb = *(const uint4*)(Bp + (size_t)row * 512 + kt + ks * 8);
      *(uint4*)(lsB + ((row * 128 + ks * 16) ^ ((row & 7) << 4))) = vb;
    }
    __syncthreads();
#pragma unroll
    for (int kk = 0; kk < 2; ++kk) {
      int kb = kk * 64 + ((lane >> 4) << 4);
      bf16x8 af[4], bfr[2];
#pragma unroll
      for (int mi = 0; mi < 4; ++mi) {
        int row = wm + mi * 16 + (lane & 15);
        af[mi] = *(const bf16x8*)(lsA + ((row * 128 + kb) ^ ((row & 7) << 4)));
      }
#pragma unroll
      for (int ni = 0; ni < 2; ++ni) {
        int row = wn + ni * 16 + (lane & 15);
        bfr[ni] = *(const bf16x8*)(lsB + ((row * 128 + kb) ^ ((row & 7) << 4)));
      }
#pragma unroll
      for (int mi = 0; mi < 4; ++mi)
#pragma unroll
        for (int ni = 0; ni < 2; ++ni)
          acc[mi][ni] = __builtin_amdgcn_mfma_f32_16x16x32_bf16(af[mi], bfr[ni], acc[mi][ni], 0, 0, 0);
    }
    __syncthreads();
  }
#pragma unroll
  for (int ni = 0; ni < 2; ++ni) {
    int o = wn + ni * 16 + (lane & 15);
    float pb = projb[o];
#pragma unroll
    for (int mi = 0; mi < 4; ++mi) {
      int ql = bm * 128 + wm + mi * 16 + ((lane >> 4) << 2);
#pragma unroll
      for (int r = 0; r < 4; ++r) {
        int qg = q0 + ql + r;
        if (qg < QTOT)
          outT[((size_t)b * QTOT + qg) * CDIM + g * 64 + o] = acc[mi][ni][r] + pb;
      }
    }
  }
}

// ---------------- final transpose: outT[b][q][c] -> out[b][c][q] ----------------
__global__ __launch_bounds__(256) void transpose_out(const float* __restrict__ outT,
                                                     float* __restrict__ out) {
  __shared__ float tl[32][33];
  int tx = threadIdx.x, ty = threadIdx.y;
  int q0 = blockIdx.x * 32, c0 = blockIdx.y * 32, b = blockIdx.z;
#pragma unroll
  for (int i = 0; i < 4; ++i) {
    int q = q0 + ty + i * 8, c = c0 + tx;
    tl[ty + i * 8][tx] = (q < QTOT) ? outT[((size_t)b * QTOT + q) * CDIM + c] : 0.0f;
  }
  __syncthreads();
#pragma unroll
  for (int i = 0; i < 4; ++i) {
    int c = c0 + ty + i * 8, q = q0 + tx;
    if (q < QTOT) out[((size_t)b * CDIM + c) * QTOT + q] = tl[tx][ty + i * 8];
  }
}

extern "C" void kernel_launch(void* const* d_in, const int* in_sizes, int n_in,
                              void* d_out, int out_size, void* d_ws, size_t ws_size,
                              hipStream_t stream) {
  const float* bev = (const float*)d_in[0];
  const float* pts = (const float*)d_in[1];
  const float* cw  = (const float*)d_in[2];
  const float* cb  = (const float*)d_in[3];
  const float* lng = (const float*)d_in[4];
  const float* lnb = (const float*)d_in[5];
  const float* pw  = (const float*)d_in[6];
  const float* pb  = (const float*)d_in[7];
  float* out = (float*)d_out;

  char* ws = (char*)d_ws;
  size_t off = 0;
  auto carve = [&](size_t bytes) -> char* {
    char* p = ws + off;
    off += (bytes + 255) & ~(size_t)255;
    return p;
  };
  __hip_bfloat16* cw_bf = (__hip_bfloat16*)carve((size_t)ODIM * CDIM * 2);
  __hip_bfloat16* bevT  = (__hip_bfloat16*)carve((size_t)2 * MPAD * CDIM * 2);
  __hip_bfloat16* pw_bf = (__hip_bfloat16*)carve((size_t)64 * 512 * 2);
  float* outT           = (float*)carve((size_t)2 * QTOT * CDIM * 4);
  size_t fixed = off;

  // pick largest chunk (rows, multiple of 128, ladder keeps coverage <= MPAD) that fits ws
  int CH = 128;
  const int ladder[4] = {2560, 1280, 640, 128};
  for (int i = 0; i < 4; ++i) {
    size_t need = fixed + (((size_t)ladder[i] * ODIM * 2 + 255) & ~(size_t)255)
                        + (((size_t)4 * ladder[i] * 512 * 2 + 255) & ~(size_t)255);
    if (need <= ws_size) { CH = ladder[i]; break; }
  }
  __hip_bfloat16* param = (__hip_bfloat16*)carve((size_t)CH * ODIM * 2);
  __hip_bfloat16* act   = (__hip_bfloat16*)carve((size_t)4 * CH * 512 * 2);

  cvt_f32_bf16<<<4096, 256, 0, stream>>>(cw, cw_bf, ODIM * CDIM);
  cvt_f32_bf16<<<128, 256, 0, stream>>>(pw, pw_bf, 64 * 512);
  transpose_bev<<<dim3(MPAD / 32, CDIM / 32, 2), dim3(32, 8), 0, stream>>>(bev, bevT);

  int nchunks = (QTOT + CH - 1) / CH;
  for (int b = 0; b < 2; ++b) {
    for (int c = 0; c < nchunks; ++c) {
      int q0 = c * CH;
      int nvalid = QTOT - q0;
      if (nvalid > CH) nvalid = CH;
      const __hip_bfloat16* Ab = bevT + ((size_t)b * MPAD + q0) * CDIM;
      gemm_param<<<dim3(CH / 128, ODIM / 128), 256, 0, stream>>>(Ab, cw_bf, cb, param);
      mix_ln<<<dim3((nvalid + 7) / 8), 256, 0, stream>>>(param, pts, lng, lnb, act, b, q0, nvalid, CH);
      gemm_proj<<<dim3(CH / 128, 4), 256, 0, stream>>>(act, pw_bf, pb, outT, b, q0, CH);
    }
  }
  transpose_out<<<dim3((QTOT + 31) / 32, CDIM / 32, 2), dim3(32, 8), 0, stream>>>(outT, out);
}

// Round 2
// 788.910 us; speedup vs baseline: 1.1185x; 1.1185x over previous
//
#include <hip/hip_runtime.h>
#include <hip/hip_bf16.h>
#include <stdint.h>

#define QTOT 10000
#define MPAD 10240
#define CDIM 256
#define ODIM 16384
#define RTOT 20096  // 157*128 : padded global rows (b*10000+q)

using f32x4  = __attribute__((ext_vector_type(4))) float;
using bf16x8 = __attribute__((ext_vector_type(8))) short;

// global -> LDS direct (16B/lane). LDS dest = wave-uniform base + lane*16.
#define GLOAD_LDS(gp, lp) __builtin_amdgcn_global_load_lds(                     \
    (const __attribute__((address_space(1))) unsigned int*)(gp),                \
    (__attribute__((address_space(3))) unsigned int*)(lp), 16, 0, 0)

// ---------------- prep kernels ----------------
__global__ void cvt_f32_bf16(const float* __restrict__ s, __hip_bfloat16* __restrict__ d, int n) {
  for (int i = blockIdx.x * blockDim.x + threadIdx.x; i < n; i += gridDim.x * blockDim.x)
    d[i] = __float2bfloat16(s[i]);
}

// bev [b][c][q] f32 -> bevT [b][q][c] bf16, rows q>=QTOT zero-filled up to MPAD
__global__ __launch_bounds__(256) void transpose_bev(const float* __restrict__ bev,
                                                     __hip_bfloat16* __restrict__ bevT) {
  __shared__ float tl[32][33];
  int tx = threadIdx.x, ty = threadIdx.y;
  int q0 = blockIdx.x * 32, c0 = blockIdx.y * 32, b = blockIdx.z;
#pragma unroll
  for (int i = 0; i < 4; ++i) {
    int c = c0 + ty + i * 8, q = q0 + tx;
    tl[ty + i * 8][tx] = (q < QTOT) ? bev[((size_t)b * CDIM + c) * QTOT + q] : 0.0f;
  }
  __syncthreads();
#pragma unroll
  for (int i = 0; i < 4; ++i) {
    int q = q0 + ty + i * 8, c = c0 + tx;
    bevT[((size_t)b * MPAD + q) * CDIM + c] = __float2bfloat16(tl[tx][ty + i * 8]);
  }
}

// ---------------- GEMM1: param[q][o] = bevT[q][:] . conv_w[o][:] + conv_b[o] ----------------
// global_load_lds staging, linear LDS dest; XOR swizzle applied on per-lane SOURCE addr.
// LDS linear block (row, kb_lin) holds A[row][kb_lin ^ (row&7)] -> identical contents to the
// verified r1 swizzled layout; ds_read side unchanged.
__global__ __launch_bounds__(256) void gemm_param(const __hip_bfloat16* __restrict__ A,
                                                  const __hip_bfloat16* __restrict__ Bw,
                                                  const float* __restrict__ convb,
                                                  __hip_bfloat16* __restrict__ P) {
  __shared__ __align__(16) unsigned char lsA[16384];
  __shared__ __align__(16) unsigned char lsB[16384];
  int t = threadIdx.x, lane = t & 63, w = t >> 6;
  int bm = blockIdx.x, bn = blockIdx.y;
  int wm = (w >> 1) * 64, wn = (w & 1) * 64;
  int srow = lane >> 3;                  // row within 8-row slab == row&7
  int kbs  = ((lane & 7) ^ srow) * 8;    // pre-swizzled source k-offset (elems)
  const __hip_bfloat16* pA = A  + (size_t)(bm * 128 + w * 32 + srow) * CDIM + kbs;
  const __hip_bfloat16* pB = Bw + (size_t)(bn * 128 + w * 32 + srow) * CDIM + kbs;
  f32x4 acc[4][4] = {};
  for (int kt = 0; kt < 256; kt += 64) {
#pragma unroll
    for (int i = 0; i < 4; ++i) {
      GLOAD_LDS(pA + (size_t)i * 8 * CDIM + kt, lsA + (w * 4 + i) * 1024);
      GLOAD_LDS(pB + (size_t)i * 8 * CDIM + kt, lsB + (w * 4 + i) * 1024);
    }
    __syncthreads();
#pragma unroll
    for (int kk = 0; kk < 2; ++kk) {
      int kb = kk * 64 + ((lane >> 4) << 4);  // byte offset of lane's 8 k-elems
      bf16x8 af[4], bfr[4];
#pragma unroll
      for (int mi = 0; mi < 4; ++mi) {
        int row = wm + mi * 16 + (lane & 15);
        af[mi] = *(const bf16x8*)(lsA + ((row * 128 + kb) ^ ((row & 7) << 4)));
      }
#pragma unroll
      for (int ni = 0; ni < 4; ++ni) {
        int row = wn + ni * 16 + (lane & 15);
        bfr[ni] = *(const bf16x8*)(lsB + ((row * 128 + kb) ^ ((row & 7) << 4)));
      }
#pragma unroll
      for (int mi = 0; mi < 4; ++mi)
#pragma unroll
        for (int ni = 0; ni < 4; ++ni)
          acc[mi][ni] = __builtin_amdgcn_mfma_f32_16x16x32_bf16(af[mi], bfr[ni], acc[mi][ni], 0, 0, 0);
    }
    __syncthreads();
  }
#pragma unroll
  for (int ni = 0; ni < 4; ++ni) {
    int col = bn * 128 + wn + ni * 16 + (lane & 15);
    float cb = convb[col];
#pragma unroll
    for (int mi = 0; mi < 4; ++mi) {
      int rb = bm * 128 + wm + mi * 16 + ((lane >> 4) << 2);
#pragma unroll
      for (int r = 0; r < 4; ++r)
        P[(size_t)(rb + r) * ODIM + col] = __float2bfloat16(acc[mi][ni][r] + cb);
    }
  }
}

// ---------------- phase 2a: mixing + LayerNorm + ReLU ----------------
// block = 8 pixels; per pixel: stage pts (8KB) + ALL 4 groups' param (32KB), 2 barriers.
// thread t: p = t>>5, c2 pair = 2*(t&31)+{0,1}
__global__ __launch_bounds__(256) void mix_ln(const __hip_bfloat16* __restrict__ P,
                                              const float* __restrict__ pts,
                                              const float* __restrict__ lng,
                                              const float* __restrict__ lnb,
                                              __hip_bfloat16* __restrict__ act,
                                              int b, int q0, int nvalid) {
  __shared__ __align__(16) float ptsl[2048];
  __shared__ __align__(16) unsigned int paraml[8192];
  int t = threadIdx.x;
  int p_ = t >> 5, cp = t & 31;
  float g0 = lng[2 * cp], g1 = lng[2 * cp + 1];
  float bb0 = lnb[2 * cp], bb1 = lnb[2 * cp + 1];
  for (int px = 0; px < 8; ++px) {
    int row = blockIdx.x * 8 + px;
    if (row >= nvalid) break;
    size_t r = (size_t)b * QTOT + q0 + row;
    const float4* ps = (const float4*)(pts + r * 2048);
    const uint4*  pg = (const uint4*)(P + (size_t)row * ODIM);
#pragma unroll
    for (int i = 0; i < 2; ++i) ((float4*)ptsl)[i * 256 + t] = ps[i * 256 + t];
#pragma unroll
    for (int i = 0; i < 8; ++i) ((uint4*)paraml)[i * 256 + t] = pg[i * 256 + t];
    __syncthreads();
#pragma unroll
    for (int g = 0; g < 4; ++g) {
      float s0 = 0.f, s1 = 0.f;
      const float* pr = ptsl + p_ * 256 + g * 64;
      const unsigned int* pp = paraml + g * 2048 + cp;
#pragma unroll 8
      for (int c1 = 0; c1 < 64; ++c1) {
        unsigned int dv = pp[c1 * 32];
        float x = pr[c1];
        s0 = fmaf(x, __uint_as_float(dv << 16), s0);
        s1 = fmaf(x, __uint_as_float(dv & 0xffff0000u), s1);
      }
      float s = s0 + s1, ss = fmaf(s0, s0, s1 * s1);
#pragma unroll
      for (int m = 1; m <= 16; m <<= 1) { s += __shfl_xor(s, m); ss += __shfl_xor(ss, m); }
      float mu  = s * 0.015625f;
      float var = ss * 0.015625f - mu * mu;
      float rs  = rsqrtf(var + 1e-5f);
      float a0 = fmaxf(0.f, (s0 - mu) * rs * g0 + bb0);
      float a1 = fmaxf(0.f, (s1 - mu) * rs * g1 + bb1);
      __hip_bfloat162 h;
      h.x = __float2bfloat16(a0);
      h.y = __float2bfloat16(a1);
      *(__hip_bfloat162*)(act + ((size_t)g * RTOT + r) * 512 + p_ * 64 + 2 * cp) = h;
    }
    __syncthreads();
  }
}

// ---------------- phase 2b: single proj GEMM over all rows -> outT[r][g*64+o] ----------------
__global__ __launch_bounds__(256) void gemm_proj(const __hip_bfloat16* __restrict__ act,
                                                 const __hip_bfloat16* __restrict__ Bp,
                                                 const float* __restrict__ projb,
                                                 float* __restrict__ outT) {
  __shared__ __align__(16) unsigned char lsA[16384];
  __shared__ __align__(16) unsigned char lsB[8192];
  int t = threadIdx.x, lane = t & 63, w = t >> 6;
  int bm = blockIdx.x, g = blockIdx.y;
  int wm = (w >> 1) * 64, wn = (w & 1) * 32;
  int srow = lane >> 3;
  int kbs  = ((lane & 7) ^ srow) * 8;
  const __hip_bfloat16* A  = act + (size_t)g * RTOT * 512;
  const __hip_bfloat16* pA = A  + (size_t)(bm * 128 + w * 32 + srow) * 512 + kbs;
  const __hip_bfloat16* pB = Bp + (size_t)(w * 16 + srow) * 512 + kbs;
  f32x4 acc[4][2] = {};
  for (int kt = 0; kt < 512; kt += 64) {
#pragma unroll
    for (int i = 0; i < 4; ++i)
      GLOAD_LDS(pA + (size_t)i * 8 * 512 + kt, lsA + (w * 4 + i) * 1024);
#pragma unroll
    for (int j = 0; j < 2; ++j)
      GLOAD_LDS(pB + (size_t)j * 8 * 512 + kt, lsB + (w * 2 + j) * 1024);
    __syncthreads();
#pragma unroll
    for (int kk = 0; kk < 2; ++kk) {
      int kb = kk * 64 + ((lane >> 4) << 4);
      bf16x8 af[4], bfr[2];
#pragma unroll
      for (int mi = 0; mi < 4; ++mi) {
        int row = wm + mi * 16 + (lane & 15);
        af[mi] = *(const bf16x8*)(lsA + ((row * 128 + kb) ^ ((row & 7) << 4)));
      }
#pragma unroll
      for (int ni = 0; ni < 2; ++ni) {
        int row = wn + ni * 16 + (lane & 15);
        bfr[ni] = *(const bf16x8*)(lsB + ((row * 128 + kb) ^ ((row & 7) << 4)));
      }
#pragma unroll
      for (int mi = 0; mi < 4; ++mi)
#pragma unroll
        for (int ni = 0; ni < 2; ++ni)
          acc[mi][ni] = __builtin_amdgcn_mfma_f32_16x16x32_bf16(af[mi], bfr[ni], acc[mi][ni], 0, 0, 0);
    }
    __syncthreads();
  }
#pragma unroll
  for (int ni = 0; ni < 2; ++ni) {
    int o = wn + ni * 16 + (lane & 15);
    float pb = projb[o];
#pragma unroll
    for (int mi = 0; mi < 4; ++mi) {
      int rb = bm * 128 + wm + mi * 16 + ((lane >> 4) << 2);
#pragma unroll
      for (int r = 0; r < 4; ++r) {
        int rg = rb + r;
        if (rg < 2 * QTOT)
          outT[(size_t)rg * CDIM + g * 64 + o] = acc[mi][ni][r] + pb;
      }
    }
  }
}

// ---------------- final transpose: outT[b][q][c] -> out[b][c][q] ----------------
__global__ __launch_bounds__(256) void transpose_out(const float* __restrict__ outT,
                                                     float* __restrict__ out) {
  __shared__ float tl[32][33];
  int tx = threadIdx.x, ty = threadIdx.y;
  int q0 = blockIdx.x * 32, c0 = blockIdx.y * 32, b = blockIdx.z;
#pragma unroll
  for (int i = 0; i < 4; ++i) {
    int q = q0 + ty + i * 8, c = c0 + tx;
    tl[ty + i * 8][tx] = (q < QTOT) ? outT[((size_t)b * QTOT + q) * CDIM + c] : 0.0f;
  }
  __syncthreads();
#pragma unroll
  for (int i = 0; i < 4; ++i) {
    int c = c0 + ty + i * 8, q = q0 + tx;
    if (q < QTOT) out[((size_t)b * CDIM + c) * QTOT + q] = tl[tx][ty + i * 8];
  }
}

extern "C" void kernel_launch(void* const* d_in, const int* in_sizes, int n_in,
                              void* d_out, int out_size, void* d_ws, size_t ws_size,
                              hipStream_t stream) {
  const float* bev = (const float*)d_in[0];
  const float* pts = (const float*)d_in[1];
  const float* cw  = (const float*)d_in[2];
  const float* cb  = (const float*)d_in[3];
  const float* lng = (const float*)d_in[4];
  const float* lnb = (const float*)d_in[5];
  const float* pw  = (const float*)d_in[6];
  const float* pb  = (const float*)d_in[7];
  float* out = (float*)d_out;

  char* ws = (char*)d_ws;
  size_t off = 0;
  auto carve = [&](size_t bytes) -> char* {
    char* p = ws + off;
    off += (bytes + 255) & ~(size_t)255;
    return p;
  };
  __hip_bfloat16* cw_bf = (__hip_bfloat16*)carve((size_t)ODIM * CDIM * 2);
  __hip_bfloat16* bevT  = (__hip_bfloat16*)carve((size_t)2 * MPAD * CDIM * 2);
  __hip_bfloat16* pw_bf = (__hip_bfloat16*)carve((size_t)64 * 512 * 2);
  float* outT           = (float*)carve((size_t)2 * QTOT * CDIM * 4);
  __hip_bfloat16* act   = (__hip_bfloat16*)carve((size_t)4 * RTOT * 512 * 2);
  size_t fixed = off;

  // pick largest chunk (rows, multiple of 128) that fits ws
  int CH = 128;
  const int ladder[4] = {2560, 1280, 640, 128};
  for (int i = 0; i < 4; ++i) {
    size_t need = fixed + (((size_t)ladder[i] * ODIM * 2 + 255) & ~(size_t)255);
    if (need <= ws_size) { CH = ladder[i]; break; }
  }
  __hip_bfloat16* param = (__hip_bfloat16*)carve((size_t)CH * ODIM * 2);

  cvt_f32_bf16<<<4096, 256, 0, stream>>>(cw, cw_bf, ODIM * CDIM);
  cvt_f32_bf16<<<128, 256, 0, stream>>>(pw, pw_bf, 64 * 512);
  transpose_bev<<<dim3(MPAD / 32, CDIM / 32, 2), dim3(32, 8), 0, stream>>>(bev, bevT);

  int nchunks = (QTOT + CH - 1) / CH;
  for (int b = 0; b < 2; ++b) {
    for (int c = 0; c < nchunks; ++c) {
      int q0 = c * CH;
      int nvalid = QTOT - q0;
      if (nvalid > CH) nvalid = CH;
      const __hip_bfloat16* Ab = bevT + ((size_t)b * MPAD + q0) * CDIM;
      gemm_param<<<dim3(CH / 128, ODIM / 128), 256, 0, stream>>>(Ab, cw_bf, cb, param);
      mix_ln<<<dim3((nvalid + 7) / 8), 256, 0, stream>>>(param, pts, lng, lnb, act, b, q0, nvalid);
    }
  }
  gemm_proj<<<dim3(RTOT / 128, 4), 256, 0, stream>>>(act, pw_bf, pb, outT);
  transpose_out<<<dim3((QTOT + 31) / 32, CDIM / 32, 2), dim3(32, 8), 0, stream>>>(outT, out);
}

// Round 3
// 568.794 us; speedup vs baseline: 1.5514x; 1.3870x over previous
//
#include <hip/hip_runtime.h>
#include <hip/hip_bf16.h>
#include <stdint.h>

#define QTOT 10000
#define MPAD 10240
#define CDIM 256
#define ODIM 16384
#define RTOT 20096  // 157*128 : padded global rows (b*10000+q)

using f32x4  = __attribute__((ext_vector_type(4))) float;
using bf16x8 = __attribute__((ext_vector_type(8))) short;

// global -> LDS direct (16B/lane). LDS dest = wave-uniform base + lane*16.
#define GLOAD_LDS(gp, lp) __builtin_amdgcn_global_load_lds(                     \
    (const __attribute__((address_space(1))) unsigned int*)(gp),                \
    (__attribute__((address_space(3))) unsigned int*)(lp), 16, 0, 0)

static __device__ __forceinline__ short f2bs(float x) {
  __hip_bfloat16 h = __float2bfloat16(x);
  return *(short*)&h;
}

// ---------------- prep kernels ----------------
__global__ void cvt_f32_bf16(const float* __restrict__ s, __hip_bfloat16* __restrict__ d, int n) {
  for (int i = blockIdx.x * blockDim.x + threadIdx.x; i < n; i += gridDim.x * blockDim.x)
    d[i] = __float2bfloat16(s[i]);
}

// conv_w row-permute + cvt: dst row o_new = g*4096 + c2*64 + c1  <-  src row g*4096 + c1*64 + c2
__global__ void cvt_permute_cw(const float* __restrict__ s, __hip_bfloat16* __restrict__ d, int n) {
  for (int i = blockIdx.x * blockDim.x + threadIdx.x; i < n; i += gridDim.x * blockDim.x) {
    int rn = i >> 8, c = i & 255;
    int ro = (rn & ~4095) | ((rn & 63) << 6) | ((rn >> 6) & 63);
    d[i] = __float2bfloat16(s[ro * 256 + c]);
  }
}

// bev [b][c][q] f32 -> bevT [b][q][c] bf16, rows q>=QTOT zero-filled up to MPAD
__global__ __launch_bounds__(256) void transpose_bev(const float* __restrict__ bev,
                                                     __hip_bfloat16* __restrict__ bevT) {
  __shared__ float tl[32][33];
  int tx = threadIdx.x, ty = threadIdx.y;
  int q0 = blockIdx.x * 32, c0 = blockIdx.y * 32, b = blockIdx.z;
#pragma unroll
  for (int i = 0; i < 4; ++i) {
    int c = c0 + ty + i * 8, q = q0 + tx;
    tl[ty + i * 8][tx] = (q < QTOT) ? bev[((size_t)b * CDIM + c) * QTOT + q] : 0.0f;
  }
  __syncthreads();
#pragma unroll
  for (int i = 0; i < 4; ++i) {
    int q = q0 + ty + i * 8, c = c0 + tx;
    bevT[((size_t)b * MPAD + q) * CDIM + c] = __float2bfloat16(tl[tx][ty + i * 8]);
  }
}

// ---------------- GEMM1: param[q][o_new] = bevT[q][:] . cw_perm[o_new][:] + cb[o_old] ------
__global__ __launch_bounds__(256) void gemm_param(const __hip_bfloat16* __restrict__ A,
                                                  const __hip_bfloat16* __restrict__ Bw,
                                                  const float* __restrict__ convb,
                                                  __hip_bfloat16* __restrict__ P) {
  __shared__ __align__(16) unsigned char lsA[16384];
  __shared__ __align__(16) unsigned char lsB[16384];
  int t = threadIdx.x, lane = t & 63, w = t >> 6;
  int bm = blockIdx.x, bn = blockIdx.y;
  int wm = (w >> 1) * 64, wn = (w & 1) * 64;
  int srow = lane >> 3;                  // row within 8-row slab == row&7
  int kbs  = ((lane & 7) ^ srow) * 8;    // pre-swizzled source k-offset (elems)
  const __hip_bfloat16* pA = A  + (size_t)(bm * 128 + w * 32 + srow) * CDIM + kbs;
  const __hip_bfloat16* pB = Bw + (size_t)(bn * 128 + w * 32 + srow) * CDIM + kbs;
  f32x4 acc[4][4] = {};
  for (int kt = 0; kt < 256; kt += 64) {
#pragma unroll
    for (int i = 0; i < 4; ++i) {
      GLOAD_LDS(pA + (size_t)i * 8 * CDIM + kt, lsA + (w * 4 + i) * 1024);
      GLOAD_LDS(pB + (size_t)i * 8 * CDIM + kt, lsB + (w * 4 + i) * 1024);
    }
    __syncthreads();
#pragma unroll
    for (int kk = 0; kk < 2; ++kk) {
      int kb = kk * 64 + ((lane >> 4) << 4);  // byte offset of lane's 8 k-elems
      bf16x8 af[4], bfr[4];
#pragma unroll
      for (int mi = 0; mi < 4; ++mi) {
        int row = wm + mi * 16 + (lane & 15);
        af[mi] = *(const bf16x8*)(lsA + ((row * 128 + kb) ^ ((row & 7) << 4)));
      }
#pragma unroll
      for (int ni = 0; ni < 4; ++ni) {
        int row = wn + ni * 16 + (lane & 15);
        bfr[ni] = *(const bf16x8*)(lsB + ((row * 128 + kb) ^ ((row & 7) << 4)));
      }
#pragma unroll
      for (int mi = 0; mi < 4; ++mi)
#pragma unroll
        for (int ni = 0; ni < 4; ++ni)
          acc[mi][ni] = __builtin_amdgcn_mfma_f32_16x16x32_bf16(af[mi], bfr[ni], acc[mi][ni], 0, 0, 0);
    }
    __syncthreads();
  }
#pragma unroll
  for (int ni = 0; ni < 4; ++ni) {
    int col = bn * 128 + wn + ni * 16 + (lane & 15);          // o_new
    int o_old = (col & ~4095) | ((col & 63) << 6) | ((col >> 6) & 63);
    float cb = convb[o_old];
#pragma unroll
    for (int mi = 0; mi < 4; ++mi) {
      int rb = bm * 128 + wm + mi * 16 + ((lane >> 4) << 2);
#pragma unroll
      for (int r = 0; r < 4; ++r)
        P[(size_t)(rb + r) * ODIM + col] = __float2bfloat16(acc[mi][ni][r] + cb);
    }
  }
}

// ---------------- phase 2a: MFMA mixing + LayerNorm + ReLU ----------------
// block = 1 pixel, 4 waves = 4 groups. Per wave: mixed^T[c2,p] = param^T[c2,c1] @ pts^T[c1,p]
// A = param (c2-major rows), B = pts (cols p, 8 of 16 used), M=64 c2, K=64 c1.
__global__ __launch_bounds__(256) void mix_mfma(const __hip_bfloat16* __restrict__ P,
                                                const float* __restrict__ pts,
                                                const float* __restrict__ lng,
                                                const float* __restrict__ lnb,
                                                __hip_bfloat16* __restrict__ act,
                                                int b, int q0) {
  __shared__ __align__(16) float ptsl[8 * 264];  // padded rows: 264 f32
  int t = threadIdx.x, lane = t & 63, g = t >> 6;
  int row = blockIdx.x;
  size_t rq = (size_t)b * QTOT + q0 + row;
  {
    const float4* ps = (const float4*)(pts + rq * 2048);
#pragma unroll
    for (int i = 0; i < 2; ++i) {
      int v = i * 256 + t;               // float4 index 0..511
      float4 val = ps[v];
      int p = v >> 6, c = (v & 63) * 4;
      *(float4*)(ptsl + p * 264 + c) = val;
    }
  }
  __syncthreads();
  int l15 = lane & 15, hi = lane >> 4;
  bf16x8 bfr[2];
#pragma unroll
  for (int kk = 0; kk < 2; ++kk) {
    bf16x8 v = {};
    if (l15 < 8) {
      const float* src = ptsl + l15 * 264 + g * 64 + kk * 32 + hi * 8;
#pragma unroll
      for (int j = 0; j < 8; ++j) v[j] = f2bs(src[j]);
    }
    bfr[kk] = v;
  }
  const __hip_bfloat16* Ap = P + (size_t)row * ODIM + g * 4096;
  f32x4 acc[4] = {};
#pragma unroll
  for (int kk = 0; kk < 2; ++kk)
#pragma unroll
    for (int mi = 0; mi < 4; ++mi) {
      bf16x8 a = *(const bf16x8*)(Ap + (size_t)(mi * 16 + l15) * 64 + kk * 32 + hi * 8);
      acc[mi] = __builtin_amdgcn_mfma_f32_16x16x32_bf16(a, bfr[kk], acc[mi], 0, 0, 0);
    }
  // LN over c2 (64 values): 16 regs/lane + reduce across hi (lanes ^16, ^32)
  float s = 0.f, ss = 0.f;
#pragma unroll
  for (int mi = 0; mi < 4; ++mi)
#pragma unroll
    for (int r = 0; r < 4; ++r) { float v = acc[mi][r]; s += v; ss = fmaf(v, v, ss); }
  s += __shfl_xor(s, 16);  ss += __shfl_xor(ss, 16);
  s += __shfl_xor(s, 32);  ss += __shfl_xor(ss, 32);
  float mu  = s * 0.015625f;
  float var = ss * 0.015625f - mu * mu;
  float rs  = rsqrtf(var + 1e-5f);
  if (l15 < 8) {
    short* ab = (short*)act + ((size_t)g * RTOT + rq) * 512 + l15 * 64;
#pragma unroll
    for (int mi = 0; mi < 4; ++mi) {
      int c2 = mi * 16 + hi * 4;
      float4 gg = *(const float4*)(lng + c2);
      float4 bb = *(const float4*)(lnb + c2);
      short4 o;
      o.x = f2bs(fmaxf(0.f, (acc[mi][0] - mu) * rs * gg.x + bb.x));
      o.y = f2bs(fmaxf(0.f, (acc[mi][1] - mu) * rs * gg.y + bb.y));
      o.z = f2bs(fmaxf(0.f, (acc[mi][2] - mu) * rs * gg.z + bb.z));
      o.w = f2bs(fmaxf(0.f, (acc[mi][3] - mu) * rs * gg.w + bb.w));
      *(short4*)(ab + c2) = o;
    }
  }
}

// ---------------- phase 2b: single proj GEMM over all rows -> outT[r][g*64+o] ----------------
__global__ __launch_bounds__(256) void gemm_proj(const __hip_bfloat16* __restrict__ act,
                                                 const __hip_bfloat16* __restrict__ Bp,
                                                 const float* __restrict__ projb,
                                                 float* __restrict__ outT) {
  __shared__ __align__(16) unsigned char lsA[16384];
  __shared__ __align__(16) unsigned char lsB[8192];
  int t = threadIdx.x, lane = t & 63, w = t >> 6;
  int bm = blockIdx.x, g = blockIdx.y;
  int wm = (w >> 1) * 64, wn = (w & 1) * 32;
  int srow = lane >> 3;
  int kbs  = ((lane & 7) ^ srow) * 8;
  const __hip_bfloat16* A  = act + (size_t)g * RTOT * 512;
  const __hip_bfloat16* pA = A  + (size_t)(bm * 128 + w * 32 + srow) * 512 + kbs;
  const __hip_bfloat16* pB = Bp + (size_t)(w * 16 + srow) * 512 + kbs;
  f32x4 acc[4][2] = {};
  for (int kt = 0; kt < 512; kt += 64) {
#pragma unroll
    for (int i = 0; i < 4; ++i)
      GLOAD_LDS(pA + (size_t)i * 8 * 512 + kt, lsA + (w * 4 + i) * 1024);
#pragma unroll
    for (int j = 0; j < 2; ++j)
      GLOAD_LDS(pB + (size_t)j * 8 * 512 + kt, lsB + (w * 2 + j) * 1024);
    __syncthreads();
#pragma unroll
    for (int kk = 0; kk < 2; ++kk) {
      int kb = kk * 64 + ((lane >> 4) << 4);
      bf16x8 af[4], bfr[2];
#pragma unroll
      for (int mi = 0; mi < 4; ++mi) {
        int row = wm + mi * 16 + (lane & 15);
        af[mi] = *(const bf16x8*)(lsA + ((row * 128 + kb) ^ ((row & 7) << 4)));
      }
#pragma unroll
      for (int ni = 0; ni < 2; ++ni) {
        int row = wn + ni * 16 + (lane & 15);
        bfr[ni] = *(const bf16x8*)(lsB + ((row * 128 + kb) ^ ((row & 7) << 4)));
      }
#pragma unroll
      for (int mi = 0; mi < 4; ++mi)
#pragma unroll
        for (int ni = 0; ni < 2; ++ni)
          acc[mi][ni] = __builtin_amdgcn_mfma_f32_16x16x32_bf16(af[mi], bfr[ni], acc[mi][ni], 0, 0, 0);
    }
    __syncthreads();
  }
#pragma unroll
  for (int ni = 0; ni < 2; ++ni) {
    int o = wn + ni * 16 + (lane & 15);
    float pb = projb[o];
#pragma unroll
    for (int mi = 0; mi < 4; ++mi) {
      int rb = bm * 128 + wm + mi * 16 + ((lane >> 4) << 2);
#pragma unroll
      for (int r = 0; r < 4; ++r) {
        int rg = rb + r;
        if (rg < 2 * QTOT)
          outT[(size_t)rg * CDIM + g * 64 + o] = acc[mi][ni][r] + pb;
      }
    }
  }
}

// ---------------- final transpose: outT[b][q][c] -> out[b][c][q] ----------------
__global__ __launch_bounds__(256) void transpose_out(const float* __restrict__ outT,
                                                     float* __restrict__ out) {
  __shared__ float tl[32][33];
  int tx = threadIdx.x, ty = threadIdx.y;
  int q0 = blockIdx.x * 32, c0 = blockIdx.y * 32, b = blockIdx.z;
#pragma unroll
  for (int i = 0; i < 4; ++i) {
    int q = q0 + ty + i * 8, c = c0 + tx;
    tl[ty + i * 8][tx] = (q < QTOT) ? outT[((size_t)b * QTOT + q) * CDIM + c] : 0.0f;
  }
  __syncthreads();
#pragma unroll
  for (int i = 0; i < 4; ++i) {
    int c = c0 + ty + i * 8, q = q0 + tx;
    if (q < QTOT) out[((size_t)b * CDIM + c) * QTOT + q] = tl[tx][ty + i * 8];
  }
}

extern "C" void kernel_launch(void* const* d_in, const int* in_sizes, int n_in,
                              void* d_out, int out_size, void* d_ws, size_t ws_size,
                              hipStream_t stream) {
  const float* bev = (const float*)d_in[0];
  const float* pts = (const float*)d_in[1];
  const float* cw  = (const float*)d_in[2];
  const float* cb  = (const float*)d_in[3];
  const float* lng = (const float*)d_in[4];
  const float* lnb = (const float*)d_in[5];
  const float* pw  = (const float*)d_in[6];
  const float* pb  = (const float*)d_in[7];
  float* out = (float*)d_out;

  char* ws = (char*)d_ws;
  size_t off = 0;
  auto carve = [&](size_t bytes) -> char* {
    char* p = ws + off;
    off += (bytes + 255) & ~(size_t)255;
    return p;
  };
  __hip_bfloat16* cw_bf = (__hip_bfloat16*)carve((size_t)ODIM * CDIM * 2);
  __hip_bfloat16* bevT  = (__hip_bfloat16*)carve((size_t)2 * MPAD * CDIM * 2);
  __hip_bfloat16* pw_bf = (__hip_bfloat16*)carve((size_t)64 * 512 * 2);
  float* outT           = (float*)carve((size_t)2 * QTOT * CDIM * 4);
  __hip_bfloat16* act   = (__hip_bfloat16*)carve((size_t)4 * RTOT * 512 * 2);
  size_t fixed = off;

  // pick largest chunk (rows, multiple of 128) that fits ws
  int CH = 128;
  const int ladder[4] = {2560, 1280, 640, 128};
  for (int i = 0; i < 4; ++i) {
    size_t need = fixed + (((size_t)ladder[i] * ODIM * 2 + 255) & ~(size_t)255);
    if (need <= ws_size) { CH = ladder[i]; break; }
  }
  __hip_bfloat16* param = (__hip_bfloat16*)carve((size_t)CH * ODIM * 2);

  cvt_permute_cw<<<4096, 256, 0, stream>>>(cw, cw_bf, ODIM * CDIM);
  cvt_f32_bf16<<<128, 256, 0, stream>>>(pw, pw_bf, 64 * 512);
  transpose_bev<<<dim3(MPAD / 32, CDIM / 32, 2), dim3(32, 8), 0, stream>>>(bev, bevT);

  int nchunks = (QTOT + CH - 1) / CH;
  for (int b = 0; b < 2; ++b) {
    for (int c = 0; c < nchunks; ++c) {
      int q0 = c * CH;
      int nvalid = QTOT - q0;
      if (nvalid > CH) nvalid = CH;
      const __hip_bfloat16* Ab = bevT + ((size_t)b * MPAD + q0) * CDIM;
      gemm_param<<<dim3(CH / 128, ODIM / 128), 256, 0, stream>>>(Ab, cw_bf, cb, param);
      mix_mfma<<<dim3(nvalid), 256, 0, stream>>>(param, pts, lng, lnb, act, b, q0);
    }
  }
  gemm_proj<<<dim3(RTOT / 128, 4), 256, 0, stream>>>(act, pw_bf, pb, outT);
  transpose_out<<<dim3((QTOT + 31) / 32, CDIM / 32, 2), dim3(32, 8), 0, stream>>>(outT, out);
}

// Round 4
// 537.250 us; speedup vs baseline: 1.6425x; 1.0587x over previous
//
#include <hip/hip_runtime.h>
#include <hip/hip_bf16.h>
#include <stdint.h>

#define QTOT 10000
#define MPAD 10240
#define CDIM 256
#define ODIM 16384
#define RTOT 20096  // 157*128 : padded global rows (b*10000+q)

using f32x4  = __attribute__((ext_vector_type(4))) float;
using bf16x8 = __attribute__((ext_vector_type(8))) short;

// global -> LDS direct (16B/lane). LDS dest = wave-uniform base + lane*16.
#define GLOAD_LDS(gp, lp) __builtin_amdgcn_global_load_lds(                     \
    (const __attribute__((address_space(1))) unsigned int*)(gp),                \
    (__attribute__((address_space(3))) unsigned int*)(lp), 16, 0, 0)

static __device__ __forceinline__ short f2bs(float x) {
  __hip_bfloat16 h = __float2bfloat16(x);
  return *(short*)&h;
}

// ---------------- prep kernels ----------------
__global__ void cvt_f32_bf16(const float* __restrict__ s, __hip_bfloat16* __restrict__ d, int n) {
  for (int i = blockIdx.x * blockDim.x + threadIdx.x; i < n; i += gridDim.x * blockDim.x)
    d[i] = __float2bfloat16(s[i]);
}

// conv_w row-permute + cvt: dst row o_new = g*4096 + c2*64 + c1  <-  src row g*4096 + c1*64 + c2
__global__ void cvt_permute_cw(const float* __restrict__ s, __hip_bfloat16* __restrict__ d, int n) {
  for (int i = blockIdx.x * blockDim.x + threadIdx.x; i < n; i += gridDim.x * blockDim.x) {
    int rn = i >> 8, c = i & 255;
    int ro = (rn & ~4095) | ((rn & 63) << 6) | ((rn >> 6) & 63);
    d[i] = __float2bfloat16(s[ro * 256 + c]);
  }
}

// bev [b][c][q] f32 -> bevT [b][q][c] bf16, rows q>=QTOT zero-filled up to MPAD
__global__ __launch_bounds__(256) void transpose_bev(const float* __restrict__ bev,
                                                     __hip_bfloat16* __restrict__ bevT) {
  __shared__ float tl[32][33];
  int tx = threadIdx.x, ty = threadIdx.y;
  int q0 = blockIdx.x * 32, c0 = blockIdx.y * 32, b = blockIdx.z;
#pragma unroll
  for (int i = 0; i < 4; ++i) {
    int c = c0 + ty + i * 8, q = q0 + tx;
    tl[ty + i * 8][tx] = (q < QTOT) ? bev[((size_t)b * CDIM + c) * QTOT + q] : 0.0f;
  }
  __syncthreads();
#pragma unroll
  for (int i = 0; i < 4; ++i) {
    int q = q0 + ty + i * 8, c = c0 + tx;
    bevT[((size_t)b * MPAD + q) * CDIM + c] = __float2bfloat16(tl[tx][ty + i * 8]);
  }
}

// ---------------- GEMM1: param[q][o_new] = bevT[q][:] . cw_perm[o_new][:] + cb[o_old] ------
// 2-phase double-buffered pipeline (T3 minimal recipe): STAGE(t+1) issued before compute(t),
// raw s_barrier + vmcnt(0) once per tile (no __syncthreads -> no forced early drain).
__global__ __launch_bounds__(256) void gemm_param(const __hip_bfloat16* __restrict__ A,
                                                  const __hip_bfloat16* __restrict__ Bw,
                                                  const float* __restrict__ convb,
                                                  __hip_bfloat16* __restrict__ P) {
  __shared__ __align__(16) unsigned char lsA[2][16384];
  __shared__ __align__(16) unsigned char lsB[2][16384];
  int t = threadIdx.x, lane = t & 63, w = t >> 6;
  int bm = blockIdx.x, bn = blockIdx.y;
  int wm = (w >> 1) * 64, wn = (w & 1) * 64;
  int srow = lane >> 3;                  // row within 8-row slab == row&7
  int kbs  = ((lane & 7) ^ srow) * 8;    // pre-swizzled source k-offset (elems)
  const __hip_bfloat16* pA = A  + (size_t)(bm * 128 + w * 32 + srow) * CDIM + kbs;
  const __hip_bfloat16* pB = Bw + (size_t)(bn * 128 + w * 32 + srow) * CDIM + kbs;
  f32x4 acc[4][4] = {};

#define STAGE_P(buf, kt) do {                                                   \
    _Pragma("unroll")                                                           \
    for (int i = 0; i < 4; ++i) {                                               \
      GLOAD_LDS(pA + (size_t)i * 8 * CDIM + (kt), lsA[buf] + (w * 4 + i) * 1024); \
      GLOAD_LDS(pB + (size_t)i * 8 * CDIM + (kt), lsB[buf] + (w * 4 + i) * 1024); \
    } } while (0)

  STAGE_P(0, 0);
  asm volatile("s_waitcnt vmcnt(0)" ::: "memory");
  __builtin_amdgcn_s_barrier();
#pragma unroll
  for (int kt = 0; kt < 4; ++kt) {
    const int cur = kt & 1;
    if (kt < 3) STAGE_P(cur ^ 1, (kt + 1) * 64);
    __builtin_amdgcn_sched_barrier(0);
#pragma unroll
    for (int kk = 0; kk < 2; ++kk) {
      int kb = kk * 64 + ((lane >> 4) << 4);  // byte offset of lane's 8 k-elems
      bf16x8 af[4], bfr[4];
#pragma unroll
      for (int mi = 0; mi < 4; ++mi) {
        int row = wm + mi * 16 + (lane & 15);
        af[mi] = *(const bf16x8*)(lsA[cur] + ((row * 128 + kb) ^ ((row & 7) << 4)));
      }
#pragma unroll
      for (int ni = 0; ni < 4; ++ni) {
        int row = wn + ni * 16 + (lane & 15);
        bfr[ni] = *(const bf16x8*)(lsB[cur] + ((row * 128 + kb) ^ ((row & 7) << 4)));
      }
#pragma unroll
      for (int mi = 0; mi < 4; ++mi)
#pragma unroll
        for (int ni = 0; ni < 4; ++ni)
          acc[mi][ni] = __builtin_amdgcn_mfma_f32_16x16x32_bf16(af[mi], bfr[ni], acc[mi][ni], 0, 0, 0);
    }
    __builtin_amdgcn_sched_barrier(0);
    if (kt < 3) asm volatile("s_waitcnt vmcnt(0)" ::: "memory");
    __builtin_amdgcn_s_barrier();
    __builtin_amdgcn_sched_barrier(0);
  }
#pragma unroll
  for (int ni = 0; ni < 4; ++ni) {
    int col = bn * 128 + wn + ni * 16 + (lane & 15);          // o_new
    int o_old = (col & ~4095) | ((col & 63) << 6) | ((col >> 6) & 63);
    float cb = convb[o_old];
#pragma unroll
    for (int mi = 0; mi < 4; ++mi) {
      int rb = bm * 128 + wm + mi * 16 + ((lane >> 4) << 2);
#pragma unroll
      for (int r = 0; r < 4; ++r)
        P[(size_t)(rb + r) * ODIM + col] = __float2bfloat16(acc[mi][ni][r] + cb);
    }
  }
#undef STAGE_P
}

// ---------------- phase 2a: MFMA mixing + LayerNorm + ReLU ----------------
// block = 1 pixel, 4 waves = 4 groups. Per wave: mixed^T[c2,p] = param^T[c2,c1] @ pts^T[c1,p]
__global__ __launch_bounds__(256) void mix_mfma(const __hip_bfloat16* __restrict__ P,
                                                const float* __restrict__ pts,
                                                const float* __restrict__ lng,
                                                const float* __restrict__ lnb,
                                                __hip_bfloat16* __restrict__ act,
                                                int b, int q0) {
  __shared__ __align__(16) float ptsl[8 * 264];  // padded rows: 264 f32
  int t = threadIdx.x, lane = t & 63, g = t >> 6;
  int row = blockIdx.x;
  size_t rq = (size_t)b * QTOT + q0 + row;
  {
    const float4* ps = (const float4*)(pts + rq * 2048);
#pragma unroll
    for (int i = 0; i < 2; ++i) {
      int v = i * 256 + t;               // float4 index 0..511
      float4 val = ps[v];
      int p = v >> 6, c = (v & 63) * 4;
      *(float4*)(ptsl + p * 264 + c) = val;
    }
  }
  __syncthreads();
  int l15 = lane & 15, hi = lane >> 4;
  bf16x8 bfr[2];
#pragma unroll
  for (int kk = 0; kk < 2; ++kk) {
    bf16x8 v = {};
    if (l15 < 8) {
      const float* src = ptsl + l15 * 264 + g * 64 + kk * 32 + hi * 8;
#pragma unroll
      for (int j = 0; j < 8; ++j) v[j] = f2bs(src[j]);
    }
    bfr[kk] = v;
  }
  const __hip_bfloat16* Ap = P + (size_t)row * ODIM + g * 4096;
  f32x4 acc[4] = {};
#pragma unroll
  for (int kk = 0; kk < 2; ++kk)
#pragma unroll
    for (int mi = 0; mi < 4; ++mi) {
      bf16x8 a = *(const bf16x8*)(Ap + (size_t)(mi * 16 + l15) * 64 + kk * 32 + hi * 8);
      acc[mi] = __builtin_amdgcn_mfma_f32_16x16x32_bf16(a, bfr[kk], acc[mi], 0, 0, 0);
    }
  // LN over c2 (64 values): 16 regs/lane + reduce across hi (lanes ^16, ^32)
  float s = 0.f, ss = 0.f;
#pragma unroll
  for (int mi = 0; mi < 4; ++mi)
#pragma unroll
    for (int r = 0; r < 4; ++r) { float v = acc[mi][r]; s += v; ss = fmaf(v, v, ss); }
  s += __shfl_xor(s, 16);  ss += __shfl_xor(ss, 16);
  s += __shfl_xor(s, 32);  ss += __shfl_xor(ss, 32);
  float mu  = s * 0.015625f;
  float var = ss * 0.015625f - mu * mu;
  float rs  = rsqrtf(var + 1e-5f);
  if (l15 < 8) {
    short* ab = (short*)act + ((size_t)g * RTOT + rq) * 512 + l15 * 64;
#pragma unroll
    for (int mi = 0; mi < 4; ++mi) {
      int c2 = mi * 16 + hi * 4;
      float4 gg = *(const float4*)(lng + c2);
      float4 bb = *(const float4*)(lnb + c2);
      short4 o;
      o.x = f2bs(fmaxf(0.f, (acc[mi][0] - mu) * rs * gg.x + bb.x));
      o.y = f2bs(fmaxf(0.f, (acc[mi][1] - mu) * rs * gg.y + bb.y));
      o.z = f2bs(fmaxf(0.f, (acc[mi][2] - mu) * rs * gg.z + bb.z));
      o.w = f2bs(fmaxf(0.f, (acc[mi][3] - mu) * rs * gg.w + bb.w));
      *(short4*)(ab + c2) = o;
    }
  }
}

// ---------------- phase 2b: single proj GEMM over all rows -> outT[r][g*64+o] ----------------
// same 2-phase dbuf pipeline, nt=8, 6 loads/tile/wave.
__global__ __launch_bounds__(256) void gemm_proj(const __hip_bfloat16* __restrict__ act,
                                                 const __hip_bfloat16* __restrict__ Bp,
                                                 const float* __restrict__ projb,
                                                 float* __restrict__ outT) {
  __shared__ __align__(16) unsigned char lsA[2][16384];
  __shared__ __align__(16) unsigned char lsB[2][8192];
  int t = threadIdx.x, lane = t & 63, w = t >> 6;
  int bm = blockIdx.x, g = blockIdx.y;
  int wm = (w >> 1) * 64, wn = (w & 1) * 32;
  int srow = lane >> 3;
  int kbs  = ((lane & 7) ^ srow) * 8;
  const __hip_bfloat16* A  = act + (size_t)g * RTOT * 512;
  const __hip_bfloat16* pA = A  + (size_t)(bm * 128 + w * 32 + srow) * 512 + kbs;
  const __hip_bfloat16* pB = Bp + (size_t)(w * 16 + srow) * 512 + kbs;
  f32x4 acc[4][2] = {};

#define STAGE_Q(buf, kt) do {                                                   \
    _Pragma("unroll")                                                           \
    for (int i = 0; i < 4; ++i)                                                 \
      GLOAD_LDS(pA + (size_t)i * 8 * 512 + (kt), lsA[buf] + (w * 4 + i) * 1024); \
    _Pragma("unroll")                                                           \
    for (int j = 0; j < 2; ++j)                                                 \
      GLOAD_LDS(pB + (size_t)j * 8 * 512 + (kt), lsB[buf] + (w * 2 + j) * 1024); \
    } while (0)

  STAGE_Q(0, 0);
  asm volatile("s_waitcnt vmcnt(0)" ::: "memory");
  __builtin_amdgcn_s_barrier();
#pragma unroll
  for (int kt = 0; kt < 8; ++kt) {
    const int cur = kt & 1;
    if (kt < 7) STAGE_Q(cur ^ 1, (kt + 1) * 64);
    __builtin_amdgcn_sched_barrier(0);
#pragma unroll
    for (int kk = 0; kk < 2; ++kk) {
      int kb = kk * 64 + ((lane >> 4) << 4);
      bf16x8 af[4], bfr[2];
#pragma unroll
      for (int mi = 0; mi < 4; ++mi) {
        int row = wm + mi * 16 + (lane & 15);
        af[mi] = *(const bf16x8*)(lsA[cur] + ((row * 128 + kb) ^ ((row & 7) << 4)));
      }
#pragma unroll
      for (int ni = 0; ni < 2; ++ni) {
        int row = wn + ni * 16 + (lane & 15);
        bfr[ni] = *(const bf16x8*)(lsB[cur] + ((row * 128 + kb) ^ ((row & 7) << 4)));
      }
#pragma unroll
      for (int mi = 0; mi < 4; ++mi)
#pragma unroll
        for (int ni = 0; ni < 2; ++ni)
          acc[mi][ni] = __builtin_amdgcn_mfma_f32_16x16x32_bf16(af[mi], bfr[ni], acc[mi][ni], 0, 0, 0);
    }
    __builtin_amdgcn_sched_barrier(0);
    if (kt < 7) asm volatile("s_waitcnt vmcnt(0)" ::: "memory");
    __builtin_amdgcn_s_barrier();
    __builtin_amdgcn_sched_barrier(0);
  }
#pragma unroll
  for (int ni = 0; ni < 2; ++ni) {
    int o = wn + ni * 16 + (lane & 15);
    float pb = projb[o];
#pragma unroll
    for (int mi = 0; mi < 4; ++mi) {
      int rb = bm * 128 + wm + mi * 16 + ((lane >> 4) << 2);
#pragma unroll
      for (int r = 0; r < 4; ++r) {
        int rg = rb + r;
        if (rg < 2 * QTOT)
          outT[(size_t)rg * CDIM + g * 64 + o] = acc[mi][ni][r] + pb;
      }
    }
  }
#undef STAGE_Q
}

// ---------------- final transpose: outT[b][q][c] -> out[b][c][q] ----------------
__global__ __launch_bounds__(256) void transpose_out(const float* __restrict__ outT,
                                                     float* __restrict__ out) {
  __shared__ float tl[32][33];
  int tx = threadIdx.x, ty = threadIdx.y;
  int q0 = blockIdx.x * 32, c0 = blockIdx.y * 32, b = blockIdx.z;
#pragma unroll
  for (int i = 0; i < 4; ++i) {
    int q = q0 + ty + i * 8, c = c0 + tx;
    tl[ty + i * 8][tx] = (q < QTOT) ? outT[((size_t)b * QTOT + q) * CDIM + c] : 0.0f;
  }
  __syncthreads();
#pragma unroll
  for (int i = 0; i < 4; ++i) {
    int c = c0 + ty + i * 8, q = q0 + tx;
    if (q < QTOT) out[((size_t)b * CDIM + c) * QTOT + q] = tl[tx][ty + i * 8];
  }
}

extern "C" void kernel_launch(void* const* d_in, const int* in_sizes, int n_in,
                              void* d_out, int out_size, void* d_ws, size_t ws_size,
                              hipStream_t stream) {
  const float* bev = (const float*)d_in[0];
  const float* pts = (const float*)d_in[1];
  const float* cw  = (const float*)d_in[2];
  const float* cb  = (const float*)d_in[3];
  const float* lng = (const float*)d_in[4];
  const float* lnb = (const float*)d_in[5];
  const float* pw  = (const float*)d_in[6];
  const float* pb  = (const float*)d_in[7];
  float* out = (float*)d_out;

  char* ws = (char*)d_ws;
  size_t off = 0;
  auto carve = [&](size_t bytes) -> char* {
    char* p = ws + off;
    off += (bytes + 255) & ~(size_t)255;
    return p;
  };
  __hip_bfloat16* cw_bf = (__hip_bfloat16*)carve((size_t)ODIM * CDIM * 2);
  __hip_bfloat16* bevT  = (__hip_bfloat16*)carve((size_t)2 * MPAD * CDIM * 2);
  __hip_bfloat16* pw_bf = (__hip_bfloat16*)carve((size_t)64 * 512 * 2);
  float* outT           = (float*)carve((size_t)2 * QTOT * CDIM * 4);
  __hip_bfloat16* act   = (__hip_bfloat16*)carve((size_t)4 * RTOT * 512 * 2);
  size_t fixed = off;

  // pick largest chunk (rows, multiple of 128) that fits ws
  int CH = 128;
  const int ladder[4] = {2560, 1280, 640, 128};
  for (int i = 0; i < 4; ++i) {
    size_t need = fixed + (((size_t)ladder[i] * ODIM * 2 + 255) & ~(size_t)255);
    if (need <= ws_size) { CH = ladder[i]; break; }
  }
  __hip_bfloat16* param = (__hip_bfloat16*)carve((size_t)CH * ODIM * 2);

  cvt_permute_cw<<<4096, 256, 0, stream>>>(cw, cw_bf, ODIM * CDIM);
  cvt_f32_bf16<<<128, 256, 0, stream>>>(pw, pw_bf, 64 * 512);
  transpose_bev<<<dim3(MPAD / 32, CDIM / 32, 2), dim3(32, 8), 0, stream>>>(bev, bevT);

  int nchunks = (QTOT + CH - 1) / CH;
  for (int b = 0; b < 2; ++b) {
    for (int c = 0; c < nchunks; ++c) {
      int q0 = c * CH;
      int nvalid = QTOT - q0;
      if (nvalid > CH) nvalid = CH;
      const __hip_bfloat16* Ab = bevT + ((size_t)b * MPAD + q0) * CDIM;
      gemm_param<<<dim3(CH / 128, ODIM / 128), 256, 0, stream>>>(Ab, cw_bf, cb, param);
      mix_mfma<<<dim3(nvalid), 256, 0, stream>>>(param, pts, lng, lnb, act, b, q0);
    }
  }
  gemm_proj<<<dim3(RTOT / 128, 4), 256, 0, stream>>>(act, pw_bf, pb, outT);
  transpose_out<<<dim3((QTOT + 31) / 32, CDIM / 32, 2), dim3(32, 8), 0, stream>>>(outT, out);
}